// Round 1
// baseline (61.992 us; speedup 1.0000x reference)
//
#include <hip/hip_runtime.h>
#include <math.h>

#define SLEN 512
#define EDIM 300
#define NC4  75   // EDIM / 4
#define NROW 12   // 3 + 4 + 5 conv kernel rows

__global__ __launch_bounds__(512, 1)
void textcnn_fused(const int*   __restrict__ sent,
                   const float* __restrict__ emb,
                   const float* __restrict__ k3, const float* __restrict__ b3,
                   const float* __restrict__ k4, const float* __restrict__ b4,
                   const float* __restrict__ k5, const float* __restrict__ b5,
                   const float* __restrict__ fcw, const float* __restrict__ fcb,
                   float* __restrict__ out)
{
    __shared__ float s_lds[NROW * SLEN];   // 12 planes of [512] scores
    __shared__ float red[8][3];            // per-wave partial maxes

    const int b = blockIdx.x;
    const int t = threadIdx.x;             // one token per thread, 512 threads

    // ---- phase 1: 12 dot products for this token --------------------------
    const int widx = sent[b * SLEN + t];
    const float4* erow = reinterpret_cast<const float4*>(emb + (size_t)widx * EDIM);
    const float4* k3v  = reinterpret_cast<const float4*>(k3);
    const float4* k4v  = reinterpret_cast<const float4*>(k4);
    const float4* k5v  = reinterpret_cast<const float4*>(k5);

    float acc[NROW];
    #pragma unroll
    for (int r = 0; r < NROW; ++r) acc[r] = 0.f;

    #pragma unroll 3
    for (int c = 0; c < NC4; ++c) {
        const float4 ev = erow[c];                 // per-lane 16B stream
        #pragma unroll
        for (int r = 0; r < 3; ++r) {              // k indices are wave-uniform
            const float4 kv = k3v[r * NC4 + c];    // -> s_load into SGPRs
            acc[r] = fmaf(ev.x, kv.x, acc[r]);
            acc[r] = fmaf(ev.y, kv.y, acc[r]);
            acc[r] = fmaf(ev.z, kv.z, acc[r]);
            acc[r] = fmaf(ev.w, kv.w, acc[r]);
        }
        #pragma unroll
        for (int r = 0; r < 4; ++r) {
            const float4 kv = k4v[r * NC4 + c];
            acc[3 + r] = fmaf(ev.x, kv.x, acc[3 + r]);
            acc[3 + r] = fmaf(ev.y, kv.y, acc[3 + r]);
            acc[3 + r] = fmaf(ev.z, kv.z, acc[3 + r]);
            acc[3 + r] = fmaf(ev.w, kv.w, acc[3 + r]);
        }
        #pragma unroll
        for (int r = 0; r < 5; ++r) {
            const float4 kv = k5v[r * NC4 + c];
            acc[7 + r] = fmaf(ev.x, kv.x, acc[7 + r]);
            acc[7 + r] = fmaf(ev.y, kv.y, acc[7 + r]);
            acc[7 + r] = fmaf(ev.z, kv.z, acc[7 + r]);
            acc[7 + r] = fmaf(ev.w, kv.w, acc[7 + r]);
        }
    }

    #pragma unroll
    for (int r = 0; r < NROW; ++r) s_lds[r * SLEN + t] = acc[r];  // conflict-free
    __syncthreads();

    // ---- phase 2: window sums, tanh, per-window max ------------------------
    const float bb3 = b3[0], bb4 = b4[0], bb5 = b5[0];
    float m3 = -1e30f, m4 = -1e30f, m5 = -1e30f;
    if (t < SLEN - 2)
        m3 = tanhf(s_lds[0 * SLEN + t] + s_lds[1 * SLEN + t + 1] +
                   s_lds[2 * SLEN + t + 2] + bb3);
    if (t < SLEN - 3)
        m4 = tanhf(s_lds[3 * SLEN + t] + s_lds[4 * SLEN + t + 1] +
                   s_lds[5 * SLEN + t + 2] + s_lds[6 * SLEN + t + 3] + bb4);
    if (t < SLEN - 4)
        m5 = tanhf(s_lds[7 * SLEN + t] + s_lds[8 * SLEN + t + 1] +
                   s_lds[9 * SLEN + t + 2] + s_lds[10 * SLEN + t + 3] +
                   s_lds[11 * SLEN + t + 4] + bb5);

    // wave (64-lane) max reduce
    #pragma unroll
    for (int off = 32; off; off >>= 1) {
        m3 = fmaxf(m3, __shfl_xor(m3, off));
        m4 = fmaxf(m4, __shfl_xor(m4, off));
        m5 = fmaxf(m5, __shfl_xor(m5, off));
    }
    if ((t & 63) == 0) {
        const int w = t >> 6;
        red[w][0] = m3; red[w][1] = m4; red[w][2] = m5;
    }
    __syncthreads();

    // ---- phase 3: logits + log_softmax (thread 0) --------------------------
    if (t == 0) {
        float f3 = red[0][0], f4 = red[0][1], f5 = red[0][2];
        #pragma unroll
        for (int w = 1; w < 8; ++w) {
            f3 = fmaxf(f3, red[w][0]);
            f4 = fmaxf(f4, red[w][1]);
            f5 = fmaxf(f5, red[w][2]);
        }
        float lg[10];
        float mx = -1e30f;
        #pragma unroll
        for (int c = 0; c < 10; ++c) {
            lg[c] = fcb[c] + f3 * fcw[c * 3 + 0] + f4 * fcw[c * 3 + 1]
                           + f5 * fcw[c * 3 + 2];
            mx = fmaxf(mx, lg[c]);
        }
        float ssum = 0.f;
        #pragma unroll
        for (int c = 0; c < 10; ++c) ssum += expf(lg[c] - mx);
        const float lse = logf(ssum);
        #pragma unroll
        for (int c = 0; c < 10; ++c) out[b * 10 + c] = lg[c] - mx - lse;
    }
}

extern "C" void kernel_launch(void* const* d_in, const int* in_sizes, int n_in,
                              void* d_out, int out_size, void* d_ws, size_t ws_size,
                              hipStream_t stream) {
    const int*   sent = (const int*)  d_in[0];
    const float* emb  = (const float*)d_in[1];
    const float* k3   = (const float*)d_in[2];
    const float* b3   = (const float*)d_in[3];
    const float* k4   = (const float*)d_in[4];
    const float* b4   = (const float*)d_in[5];
    const float* k5   = (const float*)d_in[6];
    const float* b5   = (const float*)d_in[7];
    const float* fcw  = (const float*)d_in[8];
    const float* fcb  = (const float*)d_in[9];
    float* out = (float*)d_out;

    textcnn_fused<<<256, 512, 0, stream>>>(sent, emb, k3, b3, k4, b4, k5, b5,
                                           fcw, fcb, out);
}

// Round 2
// 59.996 us; speedup vs baseline: 1.0333x; 1.0333x over previous
//
#include <hip/hip_runtime.h>
#include <math.h>

#define NSENT 256
#define SLEN  512
#define NTOK  (NSENT * SLEN)   // 131072
#define EDIM  300
#define NC4   75               // EDIM / 4
#define NROW  12               // 3 + 4 + 5 conv rows

// ---------------------------------------------------------------------------
// Kernel A: per-token scores s[r][token] = dot(emb_row(token), k_row_r)
// 64 tokens per block; wave w (0..3) handles E-chunk w (float4 cols 19/19/19/18)
// ---------------------------------------------------------------------------
__global__ __launch_bounds__(256, 4)
void textcnn_scores(const int*   __restrict__ sent,
                    const float* __restrict__ emb,
                    const float* __restrict__ k3,
                    const float* __restrict__ k4,
                    const float* __restrict__ k5,
                    float* __restrict__ s)
{
    __shared__ float part[4][64][13];   // +pad -> stride 13, conflict-free

    const int lane  = threadIdx.x & 63;
    const int wave  = threadIdx.x >> 6;
    // force scalar so k-indices compile to s_load (wave-uniform by construction)
    const int chunk = __builtin_amdgcn_readfirstlane(wave);

    const int tok0  = blockIdx.x * 64;
    const int token = tok0 + lane;

    const int widx = sent[token];
    const float4* erow = reinterpret_cast<const float4*>(emb + (size_t)widx * EDIM);
    const float4* k3v  = reinterpret_cast<const float4*>(k3);
    const float4* k4v  = reinterpret_cast<const float4*>(k4);
    const float4* k5v  = reinterpret_cast<const float4*>(k5);

    float acc[NROW];
    #pragma unroll
    for (int r = 0; r < NROW; ++r) acc[r] = 0.f;

    const int c0 = chunk * 19;

    auto dot_col = [&](int c) {
        const float4 ev = erow[c];
        #pragma unroll
        for (int r = 0; r < 3; ++r) {
            const float4 kv = k3v[r * NC4 + c];     // scalar loads
            acc[r] = fmaf(ev.x, kv.x, acc[r]);
            acc[r] = fmaf(ev.y, kv.y, acc[r]);
            acc[r] = fmaf(ev.z, kv.z, acc[r]);
            acc[r] = fmaf(ev.w, kv.w, acc[r]);
        }
        #pragma unroll
        for (int r = 0; r < 4; ++r) {
            const float4 kv = k4v[r * NC4 + c];
            acc[3+r] = fmaf(ev.x, kv.x, acc[3+r]);
            acc[3+r] = fmaf(ev.y, kv.y, acc[3+r]);
            acc[3+r] = fmaf(ev.z, kv.z, acc[3+r]);
            acc[3+r] = fmaf(ev.w, kv.w, acc[3+r]);
        }
        #pragma unroll
        for (int r = 0; r < 5; ++r) {
            const float4 kv = k5v[r * NC4 + c];
            acc[7+r] = fmaf(ev.x, kv.x, acc[7+r]);
            acc[7+r] = fmaf(ev.y, kv.y, acc[7+r]);
            acc[7+r] = fmaf(ev.z, kv.z, acc[7+r]);
            acc[7+r] = fmaf(ev.w, kv.w, acc[7+r]);
        }
    };

    #pragma unroll
    for (int i = 0; i < 18; ++i) dot_col(c0 + i);
    if (chunk < 3) dot_col(c0 + 18);    // chunks 0..2 have 19 cols, chunk 3 has 18

    #pragma unroll
    for (int r = 0; r < NROW; ++r) part[wave][lane][r] = acc[r];
    __syncthreads();

    // reduce 4 chunk-partials; each wave owns 3 rows, all 64 tokens
    const int r0 = wave * 3;
    #pragma unroll
    for (int rr = 0; rr < 3; ++rr) {
        const int r = r0 + rr;
        const float v = part[0][lane][r] + part[1][lane][r] +
                        part[2][lane][r] + part[3][lane][r];
        s[(size_t)r * NTOK + tok0 + lane] = v;   // coalesced plane store
    }
}

// ---------------------------------------------------------------------------
// Kernel B: windows + tanh + max + fc + log_softmax (one block per sentence)
// ---------------------------------------------------------------------------
__global__ __launch_bounds__(512, 1)
void textcnn_finish(const float* __restrict__ s,
                    const float* __restrict__ b3,
                    const float* __restrict__ b4,
                    const float* __restrict__ b5,
                    const float* __restrict__ fcw,
                    const float* __restrict__ fcb,
                    float* __restrict__ out)
{
    __shared__ float s_lds[NROW * SLEN];
    __shared__ float red[8][3];

    const int b = blockIdx.x;
    const int t = threadIdx.x;

    #pragma unroll
    for (int r = 0; r < NROW; ++r)
        s_lds[r * SLEN + t] = s[(size_t)r * NTOK + b * SLEN + t];
    __syncthreads();

    const float bb3 = b3[0], bb4 = b4[0], bb5 = b5[0];
    float m3 = -1e30f, m4 = -1e30f, m5 = -1e30f;
    if (t < SLEN - 2)
        m3 = tanhf(s_lds[0*SLEN + t] + s_lds[1*SLEN + t+1] +
                   s_lds[2*SLEN + t+2] + bb3);
    if (t < SLEN - 3)
        m4 = tanhf(s_lds[3*SLEN + t] + s_lds[4*SLEN + t+1] +
                   s_lds[5*SLEN + t+2] + s_lds[6*SLEN + t+3] + bb4);
    if (t < SLEN - 4)
        m5 = tanhf(s_lds[7*SLEN + t] + s_lds[8*SLEN + t+1] +
                   s_lds[9*SLEN + t+2] + s_lds[10*SLEN + t+3] +
                   s_lds[11*SLEN + t+4] + bb5);

    #pragma unroll
    for (int off = 32; off; off >>= 1) {
        m3 = fmaxf(m3, __shfl_xor(m3, off));
        m4 = fmaxf(m4, __shfl_xor(m4, off));
        m5 = fmaxf(m5, __shfl_xor(m5, off));
    }
    if ((t & 63) == 0) {
        const int w = t >> 6;
        red[w][0] = m3; red[w][1] = m4; red[w][2] = m5;
    }
    __syncthreads();

    if (t == 0) {
        float f3 = red[0][0], f4 = red[0][1], f5 = red[0][2];
        #pragma unroll
        for (int w = 1; w < 8; ++w) {
            f3 = fmaxf(f3, red[w][0]);
            f4 = fmaxf(f4, red[w][1]);
            f5 = fmaxf(f5, red[w][2]);
        }
        float lg[10];
        float mx = -1e30f;
        #pragma unroll
        for (int c = 0; c < 10; ++c) {
            lg[c] = fcb[c] + f3 * fcw[c*3+0] + f4 * fcw[c*3+1] + f5 * fcw[c*3+2];
            mx = fmaxf(mx, lg[c]);
        }
        float ssum = 0.f;
        #pragma unroll
        for (int c = 0; c < 10; ++c) ssum += expf(lg[c] - mx);
        const float lse = logf(ssum);
        #pragma unroll
        for (int c = 0; c < 10; ++c) out[b * 10 + c] = lg[c] - mx - lse;
    }
}

extern "C" void kernel_launch(void* const* d_in, const int* in_sizes, int n_in,
                              void* d_out, int out_size, void* d_ws, size_t ws_size,
                              hipStream_t stream) {
    const int*   sent = (const int*)  d_in[0];
    const float* emb  = (const float*)d_in[1];
    const float* k3   = (const float*)d_in[2];
    const float* b3   = (const float*)d_in[3];
    const float* k4   = (const float*)d_in[4];
    const float* b4   = (const float*)d_in[5];
    const float* k5   = (const float*)d_in[6];
    const float* b5   = (const float*)d_in[7];
    const float* fcw  = (const float*)d_in[8];
    const float* fcb  = (const float*)d_in[9];
    float* out = (float*)d_out;
    float* s   = (float*)d_ws;        // 12 * 131072 * 4 B = 6.3 MB

    textcnn_scores<<<NTOK / 64, 256, 0, stream>>>(sent, emb, k3, k4, k5, s);
    textcnn_finish<<<NSENT, 512, 0, stream>>>(s, b3, b4, b5, fcw, fcb, out);
}

// Round 3
// 31.935 us; speedup vs baseline: 1.9412x; 1.8787x over previous
//
#include <hip/hip_runtime.h>
#include <math.h>

#define NSENT 256
#define SLEN  512
#define VROWS 50000
#define EDIM  300
#define NC4   75               // EDIM / 4
#define NROW  12               // 3 + 4 + 5 conv rows

// ---------------------------------------------------------------------------
// Kernel A: vocab scores  s[v][r] = dot(emb_table[v], k_row_r)
// 64 vocab rows per block (sequential -> streaming reads);
// wave w (0..3) handles E-chunk w (float4 cols 19/19/19/18)
// ---------------------------------------------------------------------------
__global__ __launch_bounds__(256, 4)
void vocab_scores(const float* __restrict__ emb,
                  const float* __restrict__ k3,
                  const float* __restrict__ k4,
                  const float* __restrict__ k5,
                  float* __restrict__ s)
{
    __shared__ float part[4][64][13];   // [wave][row][r], pad 13 -> conflict-free
    __shared__ float red[64 * 13];      // reduced [row][r], pad 13

    const int lane  = threadIdx.x & 63;
    const int wave  = threadIdx.x >> 6;
    const int chunk = __builtin_amdgcn_readfirstlane(wave);  // scalar k-indices

    const int v0 = blockIdx.x * 64;
    const int v  = min(v0 + lane, VROWS - 1);   // clamp tail (dup rows, unused)

    const float4* erow = reinterpret_cast<const float4*>(emb + (size_t)v * EDIM);
    const float4* k3v  = reinterpret_cast<const float4*>(k3);
    const float4* k4v  = reinterpret_cast<const float4*>(k4);
    const float4* k5v  = reinterpret_cast<const float4*>(k5);

    float acc[NROW];
    #pragma unroll
    for (int r = 0; r < NROW; ++r) acc[r] = 0.f;

    const int c0 = chunk * 19;

    auto dot_col = [&](int c) {
        const float4 ev = erow[c];
        #pragma unroll
        for (int r = 0; r < 3; ++r) {
            const float4 kv = k3v[r * NC4 + c];     // s_load (wave-uniform)
            acc[r] = fmaf(ev.x, kv.x, acc[r]);
            acc[r] = fmaf(ev.y, kv.y, acc[r]);
            acc[r] = fmaf(ev.z, kv.z, acc[r]);
            acc[r] = fmaf(ev.w, kv.w, acc[r]);
        }
        #pragma unroll
        for (int r = 0; r < 4; ++r) {
            const float4 kv = k4v[r * NC4 + c];
            acc[3+r] = fmaf(ev.x, kv.x, acc[3+r]);
            acc[3+r] = fmaf(ev.y, kv.y, acc[3+r]);
            acc[3+r] = fmaf(ev.z, kv.z, acc[3+r]);
            acc[3+r] = fmaf(ev.w, kv.w, acc[3+r]);
        }
        #pragma unroll
        for (int r = 0; r < 5; ++r) {
            const float4 kv = k5v[r * NC4 + c];
            acc[7+r] = fmaf(ev.x, kv.x, acc[7+r]);
            acc[7+r] = fmaf(ev.y, kv.y, acc[7+r]);
            acc[7+r] = fmaf(ev.z, kv.z, acc[7+r]);
            acc[7+r] = fmaf(ev.w, kv.w, acc[7+r]);
        }
    };

    #pragma unroll
    for (int i = 0; i < 18; ++i) dot_col(c0 + i);
    if (chunk < 3) dot_col(c0 + 18);    // chunks 0..2: 19 cols, chunk 3: 18

    #pragma unroll
    for (int r = 0; r < NROW; ++r) part[wave][lane][r] = acc[r];
    __syncthreads();

    // reduce the 4 E-chunk partials; wave w owns rows r0..r0+2, all 64 v's
    const int r0 = wave * 3;
    #pragma unroll
    for (int rr = 0; rr < 3; ++rr) {
        const int r = r0 + rr;
        red[lane * 13 + r] = part[0][lane][r] + part[1][lane][r] +
                             part[2][lane][r] + part[3][lane][r];
    }
    __syncthreads();

    // coalesced store of the 64x12 block ([V][12] row-major)
    for (int j = threadIdx.x; j < 64 * NROW; j += 256) {
        const int gi = v0 * NROW + j;
        if (gi < VROWS * NROW)
            s[gi] = red[(j / NROW) * 13 + (j % NROW)];
    }
}

// ---------------------------------------------------------------------------
// Kernel B: gather 48B/token from L2-resident score table, then
// windows + tanh + max + fc + log_softmax (one block per sentence)
// ---------------------------------------------------------------------------
__global__ __launch_bounds__(512, 1)
void textcnn_finish(const int*   __restrict__ sent,
                    const float* __restrict__ s,
                    const float* __restrict__ b3,
                    const float* __restrict__ b4,
                    const float* __restrict__ b5,
                    const float* __restrict__ fcw,
                    const float* __restrict__ fcb,
                    float* __restrict__ out)
{
    __shared__ float s_lds[NROW * SLEN];
    __shared__ float red[8][3];

    const int b = blockIdx.x;
    const int t = threadIdx.x;

    const int widx = sent[b * SLEN + t];
    const float4* sv = reinterpret_cast<const float4*>(s + (size_t)widx * NROW);
    const float4 sa = sv[0], sb = sv[1], sc = sv[2];

    s_lds[ 0*SLEN + t] = sa.x;  s_lds[ 1*SLEN + t] = sa.y;
    s_lds[ 2*SLEN + t] = sa.z;  s_lds[ 3*SLEN + t] = sa.w;
    s_lds[ 4*SLEN + t] = sb.x;  s_lds[ 5*SLEN + t] = sb.y;
    s_lds[ 6*SLEN + t] = sb.z;  s_lds[ 7*SLEN + t] = sb.w;
    s_lds[ 8*SLEN + t] = sc.x;  s_lds[ 9*SLEN + t] = sc.y;
    s_lds[10*SLEN + t] = sc.z;  s_lds[11*SLEN + t] = sc.w;
    __syncthreads();

    const float bb3 = b3[0], bb4 = b4[0], bb5 = b5[0];
    float m3 = -1e30f, m4 = -1e30f, m5 = -1e30f;
    if (t < SLEN - 2)
        m3 = tanhf(s_lds[0*SLEN + t] + s_lds[1*SLEN + t+1] +
                   s_lds[2*SLEN + t+2] + bb3);
    if (t < SLEN - 3)
        m4 = tanhf(s_lds[3*SLEN + t] + s_lds[4*SLEN + t+1] +
                   s_lds[5*SLEN + t+2] + s_lds[6*SLEN + t+3] + bb4);
    if (t < SLEN - 4)
        m5 = tanhf(s_lds[7*SLEN + t] + s_lds[8*SLEN + t+1] +
                   s_lds[9*SLEN + t+2] + s_lds[10*SLEN + t+3] +
                   s_lds[11*SLEN + t+4] + bb5);

    #pragma unroll
    for (int off = 32; off; off >>= 1) {
        m3 = fmaxf(m3, __shfl_xor(m3, off));
        m4 = fmaxf(m4, __shfl_xor(m4, off));
        m5 = fmaxf(m5, __shfl_xor(m5, off));
    }
    if ((t & 63) == 0) {
        const int w = t >> 6;
        red[w][0] = m3; red[w][1] = m4; red[w][2] = m5;
    }
    __syncthreads();

    if (t == 0) {
        float f3 = red[0][0], f4 = red[0][1], f5 = red[0][2];
        #pragma unroll
        for (int w = 1; w < 8; ++w) {
            f3 = fmaxf(f3, red[w][0]);
            f4 = fmaxf(f4, red[w][1]);
            f5 = fmaxf(f5, red[w][2]);
        }
        float lg[10];
        float mx = -1e30f;
        #pragma unroll
        for (int c = 0; c < 10; ++c) {
            lg[c] = fcb[c] + f3 * fcw[c*3+0] + f4 * fcw[c*3+1] + f5 * fcw[c*3+2];
            mx = fmaxf(mx, lg[c]);
        }
        float ssum = 0.f;
        #pragma unroll
        for (int c = 0; c < 10; ++c) ssum += expf(lg[c] - mx);
        const float lse = logf(ssum);
        #pragma unroll
        for (int c = 0; c < 10; ++c) out[b * 10 + c] = lg[c] - mx - lse;
    }
}

extern "C" void kernel_launch(void* const* d_in, const int* in_sizes, int n_in,
                              void* d_out, int out_size, void* d_ws, size_t ws_size,
                              hipStream_t stream) {
    const int*   sent = (const int*)  d_in[0];
    const float* emb  = (const float*)d_in[1];
    const float* k3   = (const float*)d_in[2];
    const float* b3   = (const float*)d_in[3];
    const float* k4   = (const float*)d_in[4];
    const float* b4   = (const float*)d_in[5];
    const float* k5   = (const float*)d_in[6];
    const float* b5   = (const float*)d_in[7];
    const float* fcw  = (const float*)d_in[8];
    const float* fcb  = (const float*)d_in[9];
    float* out = (float*)d_out;
    float* s   = (float*)d_ws;        // VROWS * 12 * 4 B = 2.4 MB

    const int nblk = (VROWS + 63) / 64;   // 782
    vocab_scores<<<nblk, 256, 0, stream>>>(emb, k3, k4, k5, s);
    textcnn_finish<<<NSENT, 512, 0, stream>>>(sent, s, b3, b4, b5, fcw, fcb, out);
}

// Round 4
// 28.437 us; speedup vs baseline: 2.1800x; 1.1230x over previous
//
#include <hip/hip_runtime.h>
#include <math.h>

#define NSENT 256
#define SLEN  512
#define VROWS 50000
#define EDIM  300
#define NC4   75               // EDIM / 4
#define NROW  12               // 3 + 4 + 5 conv rows

// ---------------------------------------------------------------------------
// Kernel A: vocab scores  s[v][r] = dot(emb_table[v], k_row_r)
// 64 vocab rows per block; wave w (0..3) handles E-chunk w (19/19/19/18 f4s).
// All chunk loads are hoisted into a register batch -> ~19 loads in flight
// per lane (round-3 version had VGPR=28 -> ~2-3 in flight, latency-bound).
// ---------------------------------------------------------------------------
__global__ __launch_bounds__(256, 4)
void vocab_scores(const float* __restrict__ emb,
                  const float* __restrict__ k3,
                  const float* __restrict__ k4,
                  const float* __restrict__ k5,
                  float* __restrict__ s)
{
    __shared__ float part[4][64][13];   // [wave][row][r], pad 13 -> conflict-free
    __shared__ float red[64 * 13];      // reduced [row][r]

    const int lane  = threadIdx.x & 63;
    const int wave  = threadIdx.x >> 6;
    const int chunk = __builtin_amdgcn_readfirstlane(wave);  // scalar k-indices

    const int v0 = blockIdx.x * 64;
    const int v  = min(v0 + lane, VROWS - 1);   // clamp tail (dup rows, unused)

    const float4* erow = reinterpret_cast<const float4*>(emb + (size_t)v * EDIM);
    const float4* k3v  = reinterpret_cast<const float4*>(k3);
    const float4* k4v  = reinterpret_cast<const float4*>(k4);
    const float4* k5v  = reinterpret_cast<const float4*>(k5);

    const int  c0   = chunk * 19;
    const bool full = (chunk < 3);      // wave-uniform branch

    // ---- batch-issue all embedding loads for this chunk -------------------
    float4 ev[18];
    #pragma unroll
    for (int i = 0; i < 18; ++i) ev[i] = erow[c0 + i];
    float4 evL;
    if (full) evL = erow[c0 + 18];

    float acc[NROW];
    #pragma unroll
    for (int r = 0; r < NROW; ++r) acc[r] = 0.f;

    auto fma_col = [&](const float4 ev_, int c) {
        #pragma unroll
        for (int r = 0; r < 3; ++r) {
            const float4 kv = k3v[r * NC4 + c];     // s_load (wave-uniform)
            acc[r] = fmaf(ev_.x, kv.x, acc[r]);
            acc[r] = fmaf(ev_.y, kv.y, acc[r]);
            acc[r] = fmaf(ev_.z, kv.z, acc[r]);
            acc[r] = fmaf(ev_.w, kv.w, acc[r]);
        }
        #pragma unroll
        for (int r = 0; r < 4; ++r) {
            const float4 kv = k4v[r * NC4 + c];
            acc[3+r] = fmaf(ev_.x, kv.x, acc[3+r]);
            acc[3+r] = fmaf(ev_.y, kv.y, acc[3+r]);
            acc[3+r] = fmaf(ev_.z, kv.z, acc[3+r]);
            acc[3+r] = fmaf(ev_.w, kv.w, acc[3+r]);
        }
        #pragma unroll
        for (int r = 0; r < 5; ++r) {
            const float4 kv = k5v[r * NC4 + c];
            acc[7+r] = fmaf(ev_.x, kv.x, acc[7+r]);
            acc[7+r] = fmaf(ev_.y, kv.y, acc[7+r]);
            acc[7+r] = fmaf(ev_.z, kv.z, acc[7+r]);
            acc[7+r] = fmaf(ev_.w, kv.w, acc[7+r]);
        }
    };

    #pragma unroll
    for (int i = 0; i < 18; ++i) fma_col(ev[i], c0 + i);
    if (full) fma_col(evL, c0 + 18);

    #pragma unroll
    for (int r = 0; r < NROW; ++r) part[wave][lane][r] = acc[r];
    __syncthreads();

    // reduce the 4 E-chunk partials; wave w owns rows r0..r0+2, all 64 v's
    const int r0 = wave * 3;
    #pragma unroll
    for (int rr = 0; rr < 3; ++rr) {
        const int r = r0 + rr;
        red[lane * 13 + r] = part[0][lane][r] + part[1][lane][r] +
                             part[2][lane][r] + part[3][lane][r];
    }
    __syncthreads();

    // coalesced store of the 64x12 block ([V][12] row-major)
    for (int j = threadIdx.x; j < 64 * NROW; j += 256) {
        const int gi = v0 * NROW + j;
        if (gi < VROWS * NROW)
            s[gi] = red[(j / NROW) * 13 + (j % NROW)];
    }
}

// ---------------------------------------------------------------------------
// Kernel B: gather 48B/token from L3-resident score table, then
// windows + tanh + max + fc + log_softmax. 1024 threads (16 waves) per
// sentence for 2x the occupancy / gather MLP of the 512-thread version.
// Gather index L = j*512 + token  (j = which float4 of the row's 3).
// ---------------------------------------------------------------------------
__global__ __launch_bounds__(1024, 1)
void textcnn_finish(const int*   __restrict__ sent,
                    const float* __restrict__ s,
                    const float* __restrict__ b3,
                    const float* __restrict__ b4,
                    const float* __restrict__ b5,
                    const float* __restrict__ fcw,
                    const float* __restrict__ fcb,
                    float* __restrict__ out)
{
    __shared__ float s_lds[NROW * SLEN];
    __shared__ float red[8][3];

    const int b = blockIdx.x;
    const int t = threadIdx.x;

    auto gather = [&](int token, int j) {
        const int widx = sent[b * SLEN + token];
        const float4 v = reinterpret_cast<const float4*>(s + (size_t)widx * NROW)[j];
        s_lds[(4*j + 0) * SLEN + token] = v.x;
        s_lds[(4*j + 1) * SLEN + token] = v.y;
        s_lds[(4*j + 2) * SLEN + token] = v.z;
        s_lds[(4*j + 3) * SLEN + token] = v.w;
    };

    gather(t & 511, t >> 9);            // j = 0,1 across the 1024 threads
    if (t < SLEN) gather(t, 2);         // j = 2
    __syncthreads();

    if (t < SLEN) {
        const float bb3 = b3[0], bb4 = b4[0], bb5 = b5[0];
        float m3 = -1e30f, m4 = -1e30f, m5 = -1e30f;
        if (t < SLEN - 2)
            m3 = tanhf(s_lds[0*SLEN + t] + s_lds[1*SLEN + t+1] +
                       s_lds[2*SLEN + t+2] + bb3);
        if (t < SLEN - 3)
            m4 = tanhf(s_lds[3*SLEN + t] + s_lds[4*SLEN + t+1] +
                       s_lds[5*SLEN + t+2] + s_lds[6*SLEN + t+3] + bb4);
        if (t < SLEN - 4)
            m5 = tanhf(s_lds[7*SLEN + t] + s_lds[8*SLEN + t+1] +
                       s_lds[9*SLEN + t+2] + s_lds[10*SLEN + t+3] +
                       s_lds[11*SLEN + t+4] + bb5);

        #pragma unroll
        for (int off = 32; off; off >>= 1) {
            m3 = fmaxf(m3, __shfl_xor(m3, off));
            m4 = fmaxf(m4, __shfl_xor(m4, off));
            m5 = fmaxf(m5, __shfl_xor(m5, off));
        }
        if ((t & 63) == 0) {
            const int w = t >> 6;
            red[w][0] = m3; red[w][1] = m4; red[w][2] = m5;
        }
    }
    __syncthreads();

    if (t == 0) {
        float f3 = red[0][0], f4 = red[0][1], f5 = red[0][2];
        #pragma unroll
        for (int w = 1; w < 8; ++w) {
            f3 = fmaxf(f3, red[w][0]);
            f4 = fmaxf(f4, red[w][1]);
            f5 = fmaxf(f5, red[w][2]);
        }
        float lg[10];
        float mx = -1e30f;
        #pragma unroll
        for (int c = 0; c < 10; ++c) {
            lg[c] = fcb[c] + f3 * fcw[c*3+0] + f4 * fcw[c*3+1] + f5 * fcw[c*3+2];
            mx = fmaxf(mx, lg[c]);
        }
        float ssum = 0.f;
        #pragma unroll
        for (int c = 0; c < 10; ++c) ssum += expf(lg[c] - mx);
        const float lse = logf(ssum);
        #pragma unroll
        for (int c = 0; c < 10; ++c) out[b * 10 + c] = lg[c] - mx - lse;
    }
}

extern "C" void kernel_launch(void* const* d_in, const int* in_sizes, int n_in,
                              void* d_out, int out_size, void* d_ws, size_t ws_size,
                              hipStream_t stream) {
    const int*   sent = (const int*)  d_in[0];
    const float* emb  = (const float*)d_in[1];
    const float* k3   = (const float*)d_in[2];
    const float* b3   = (const float*)d_in[3];
    const float* k4   = (const float*)d_in[4];
    const float* b4   = (const float*)d_in[5];
    const float* k5   = (const float*)d_in[6];
    const float* b5   = (const float*)d_in[7];
    const float* fcw  = (const float*)d_in[8];
    const float* fcb  = (const float*)d_in[9];
    float* out = (float*)d_out;
    float* s   = (float*)d_ws;        // VROWS * 12 * 4 B = 2.4 MB

    const int nblk = (VROWS + 63) / 64;   // 782
    vocab_scores<<<nblk, 256, 0, stream>>>(emb, k3, k4, k5, s);
    textcnn_finish<<<NSENT, 1024, 0, stream>>>(sent, s, b3, b4, b5, fcw, fcb, out);
}